// Round 5
// baseline (206.861 us; speedup 1.0000x reference)
//
#include <hip/hip_runtime.h>
#include <math.h>

// MoE top-2-of-8: B=1024, I=512, H=2048, O=512, E=8, K=2.
// R5: (a) fast 64x64-tile transpose prologue (4 loads in flight/thread,
// full-cacheline stores); (b) double-buffered LDS in both GEMMs: GL_LDS(k+1)
// issued before MFMA(k), drained at the next barrier -> global latency hidden
// even at ~2 working blocks/CU. GEMM fragment math identical to R4 (verified).

#define B_TOK 1024
#define I_DIM 512
#define H_DIM 2048
#define O_DIM 512
#define E_NUM 8

#define WS_COUNTS   0                    // 8 ints
#define WS_OFFSETS  32                   // 8 ints
#define WS_TOK_E    64                   // [1024][2] int
#define WS_TOK_W    8256                 // [1024][2] float
#define WS_SLOT_TOK 16448                // [2048] int
#define WS_SLOT_WT  24640                // [2048] float
#define WS_XB       65536                // [1024][512] bf16 = 1 MB
#define WS_HB       (WS_XB + 1048576)    // [2048][2048] bf16 = 8 MB
#define WS_W1T      (WS_HB + 8388608)    // [8][2048][512] bf16 = 16 MB ([n][k])
#define WS_W2T      (WS_W1T + 16777216)  // [8][512][2048] bf16 = 16 MB ([n][k])

typedef __attribute__((ext_vector_type(8))) __bf16 bf16x8;
typedef __attribute__((ext_vector_type(4))) __bf16 bf16x4;
typedef __attribute__((ext_vector_type(4))) float f32x4;

#define MFMA16 __builtin_amdgcn_mfma_f32_16x16x32_bf16

// async global->LDS, 16B/lane; LDS dest is wave-uniform base + lane*16 (m104)
#define GL_LDS16(gp, lp)                                                      \
    __builtin_amdgcn_global_load_lds(                                         \
        (const __attribute__((address_space(1))) unsigned int*)(gp),          \
        (__attribute__((address_space(3))) unsigned int*)(lp), 16, 0, 0)

// ---------------------------------------------------------------------------
// Prologue: blocks [0,2048) transpose W1 (64x64 tiles), [2048,4096) W2,
// [4096,4608) zero out + convert x + zero counts.
__global__ __launch_bounds__(256) void prologue_kernel(
    const float* __restrict__ W1, const float* __restrict__ W2,
    const float4* __restrict__ x4,
    __bf16* __restrict__ W1t, __bf16* __restrict__ W2t,
    __bf16* __restrict__ xb, float4* __restrict__ out4, int* __restrict__ cnt)
{
    __shared__ __bf16 T[64][72];
    int id = blockIdx.x;
    const int tid = threadIdx.x;
    if (id >= 4096) {
        const int idx = (id - 4096) * 256 + tid;     // 131072 float4s
        out4[idx] = float4{0.f, 0.f, 0.f, 0.f};
        float4 v = x4[idx];
        bf16x4 o;
        o[0] = (__bf16)v.x; o[1] = (__bf16)v.y;
        o[2] = (__bf16)v.z; o[3] = (__bf16)v.w;
        *(bf16x4*)(xb + (size_t)idx * 4) = o;
        if (id == 4096 && tid < 16) cnt[tid] = 0;
        return;
    }
    const float* W;
    __bf16* Wt;
    int R, C;
    if (id < 2048) { W = W1; Wt = W1t; R = I_DIM; C = H_DIM; }
    else { id -= 2048; W = W2; Wt = W2t; R = H_DIM; C = O_DIM; }
    const int e = id >> 8;               // 256 tiles (64x64) per expert
    const int t = id & 255;
    const int tpr = C >> 6;
    const int r0 = (t / tpr) * 64;
    const int c0 = (t % tpr) * 64;
    W  += (size_t)e * R * C;
    Wt += (size_t)e * R * C;

    const int ri = tid >> 2;             // 0..63 input row
    const int cb = tid & 3;
    const float* src = W + (size_t)(r0 + ri) * C + c0 + cb * 4;
    float4 v[4];
#pragma unroll
    for (int j = 0; j < 4; ++j) v[j] = *(const float4*)(src + j * 16);
#pragma unroll
    for (int j = 0; j < 4; ++j) {
        int c = cb * 4 + j * 16;
        T[c + 0][ri] = (__bf16)v[j].x;
        T[c + 1][ri] = (__bf16)v[j].y;
        T[c + 2][ri] = (__bf16)v[j].z;
        T[c + 3][ri] = (__bf16)v[j].w;
    }
    __syncthreads();
    const int n  = tid >> 2;             // 0..63 output row (= input col)
    const int kb = tid & 3;
    bf16x8 o0 = *(const bf16x8*)&T[n][kb * 16];
    bf16x8 o1 = *(const bf16x8*)&T[n][kb * 16 + 8];
    __bf16* dst = Wt + (size_t)(c0 + n) * R + r0 + kb * 16;
    *(bf16x8*)dst = o0;
    *(bf16x8*)(dst + 8) = o1;
}

// One wave per token: logits = x @ Wg + bg, top-2, renormalized softmax weights.
__global__ __launch_bounds__(256) void gating_kernel(
    const float* __restrict__ x, const float* __restrict__ Wg,
    const float* __restrict__ bg,
    int* __restrict__ counts, int* __restrict__ tok_e, float* __restrict__ tok_w)
{
    const int lane = threadIdx.x & 63;
    const int t = blockIdx.x * 4 + (threadIdx.x >> 6);
    const float* xr = x + (size_t)t * I_DIM;
    float acc[8];
#pragma unroll
    for (int e = 0; e < 8; ++e) acc[e] = 0.f;
    for (int i = lane; i < I_DIM; i += 64) {
        float xv = xr[i];
        const float4* wr = (const float4*)(Wg + (size_t)i * 8);
        float4 wa = wr[0], wb = wr[1];
        acc[0] = fmaf(xv, wa.x, acc[0]);
        acc[1] = fmaf(xv, wa.y, acc[1]);
        acc[2] = fmaf(xv, wa.z, acc[2]);
        acc[3] = fmaf(xv, wa.w, acc[3]);
        acc[4] = fmaf(xv, wb.x, acc[4]);
        acc[5] = fmaf(xv, wb.y, acc[5]);
        acc[6] = fmaf(xv, wb.z, acc[6]);
        acc[7] = fmaf(xv, wb.w, acc[7]);
    }
#pragma unroll
    for (int off = 32; off > 0; off >>= 1)
#pragma unroll
        for (int e = 0; e < 8; ++e)
            acc[e] += __shfl_xor(acc[e], off, 64);
    if (lane == 0) {
        float l[8];
#pragma unroll
        for (int e = 0; e < 8; ++e) l[e] = acc[e] + bg[e];
        int e0 = 0;
        for (int e = 1; e < 8; ++e) if (l[e] > l[e0]) e0 = e;
        int e1 = (e0 == 0) ? 1 : 0;
        for (int e = 0; e < 8; ++e) {
            if (e == e0) continue;
            if (l[e] > l[e1]) e1 = e;
        }
        float w0 = 1.f / (1.f + expf(l[e1] - l[e0]));  // p0/(p0+p1)
        tok_e[t * 2]     = e0;
        tok_e[t * 2 + 1] = e1;
        tok_w[t * 2]     = w0;
        tok_w[t * 2 + 1] = 1.f - w0;
        atomicAdd(&counts[e0], 1);
        atomicAdd(&counts[e1], 1);
    }
}

// Single block: prefix over 8 counts, scatter into compact per-expert slot lists.
__global__ __launch_bounds__(1024) void scatter_kernel(
    const int* __restrict__ counts, const int* __restrict__ tok_e,
    const float* __restrict__ tok_w,
    int* __restrict__ offsets, int* __restrict__ slot_token,
    float* __restrict__ slot_wt)
{
    __shared__ int soff[8];
    __shared__ int scur[8];
    const int tid = threadIdx.x;
    if (tid == 0) {
        int run = 0;
        for (int e = 0; e < 8; ++e) { soff[e] = run; run += counts[e]; }
    }
    if (tid < 8) scur[tid] = 0;
    __syncthreads();
    if (tid < 8) offsets[tid] = soff[tid];
#pragma unroll
    for (int k = 0; k < 2; ++k) {
        int e = tok_e[tid * 2 + k];
        int pos = atomicAdd(&scur[e], 1);
        int slot = soff[e] + pos;
        slot_token[slot] = tid;
        slot_wt[slot] = tok_w[tid * 2 + k];
    }
}

// ---------------------------------------------------------------------------
// Double-buffered m97-style MFMA GEMM.  BM=64, BK=32, 256 threads (4 waves).
// LDS element (r, kchunk c) at phys chunk c ^ ((r>>1)&3) (bank-minimal b128).
// IS_FC1:  A=xb gathered, B=W1t[e] [n][k], BN=128, Out=hb (relu+bias)
// !IS_FC1: A=hb direct,   B=W2t[e] [n][k], BN=64, split-K=2, Out=out f32 atomic
template <bool IS_FC1>
__global__ __launch_bounds__(256) void moe_gemm(
    const __bf16* __restrict__ A, const __bf16* __restrict__ Wt,
    const float* __restrict__ bias,
    const int* __restrict__ counts, const int* __restrict__ offsets,
    const int* __restrict__ slot_token, const float* __restrict__ slot_wt,
    void* __restrict__ out_)
{
    constexpr int N     = IS_FC1 ? H_DIM : O_DIM;
    constexpr int K     = IS_FC1 ? I_DIM : H_DIM;     // also A row stride
    constexpr int BN    = IS_FC1 ? 128 : 64;
    constexpr int ITERS = IS_FC1 ? 16 : 32;           // BK=32; fc2 chunk=1024
    constexpr int NB    = IS_FC1 ? 4 : 2;             // b-frags per wave
    constexpr int ASZ   = 64 * 32;                    // elems per A buffer
    constexpr int BSZ   = BN * 32;

    const int e  = IS_FC1 ? blockIdx.z : (blockIdx.z & 7);
    const int kc = IS_FC1 ? 0 : (int)(blockIdx.z >> 3);
    const int Me = counts[e];
    const int m0 = blockIdx.y * 64;
    if (m0 >= Me) return;
    const int n0 = blockIdx.x * BN;
    const int off = offsets[e];
    const int k0 = kc * 1024;

    __shared__ __align__(16) __bf16 As[2 * ASZ];
    __shared__ __align__(16) __bf16 Bs[2 * BSZ];
    __shared__ int toks[64];

    const int tid = threadIdx.x;
    const int lane = tid & 63, w = tid >> 6;
    if (tid < 64) {
        int m = m0 + tid;
        if (m >= Me) m = Me - 1;          // clamp: loads valid, stores guarded
        toks[tid] = slot_token[off + m];
    }
    __syncthreads();

    // ---- staging setup: per-lane global ptrs, wave-uniform LDS bases ----
    const int srow = lane >> 2;                        // row within 16-row inst
    const int ar = w * 16 + srow;
    const int ac = (lane & 3) ^ ((ar >> 1) & 3);       // memory k-chunk
    const __bf16* a_g;
    if (IS_FC1) {
        a_g = A + (size_t)toks[ar] * K + ac * 8;
    } else {
        int m = m0 + ar;
        if (m >= Me) m = Me - 1;
        a_g = A + (size_t)(off + m) * K + k0 + ac * 8;
    }
    const __bf16* Wte = Wt + (size_t)e * N * K;
    const int br0 = w * (IS_FC1 ? 32 : 16) + srow;
    const __bf16* b_g0 = Wte + (size_t)(n0 + br0) * K + k0
                         + (((lane & 3) ^ ((br0 >> 1) & 3)) * 8);
    const __bf16* b_g1 = nullptr;
    if (IS_FC1) {
        const int br1 = br0 + 16;
        b_g1 = Wte + (size_t)(n0 + br1) * K + k0
               + (((lane & 3) ^ ((br1 >> 1) & 3)) * 8);
    }
    const int as_off  = w * 16 * 32;
    const int bs_off0 = w * (IS_FC1 ? 32 : 16) * 32;
    const int bs_off1 = IS_FC1 ? (w * 32 + 16) * 32 : 0;

    // ---- fragment read offsets (swizzled, within one buffer) ----
    const int l15 = lane & 15, q = lane >> 4;
    const int wm = (w >> 1) * 32;
    const int wn = (w & 1) * (IS_FC1 ? 64 : 32);
    int aoff[2], boff[NB];
#pragma unroll
    for (int i = 0; i < 2; ++i) {
        int m = wm + i * 16 + l15;
        aoff[i] = m * 32 + (q ^ ((m >> 1) & 3)) * 8;
    }
#pragma unroll
    for (int j = 0; j < NB; ++j) {
        int n = wn + j * 16 + l15;
        boff[j] = n * 32 + (q ^ ((n >> 1) & 3)) * 8;
    }

    f32x4 acc[2][NB] = {};

    // initial stage (K-step 0) into buffer 0
    GL_LDS16(a_g, &As[as_off]);
    GL_LDS16(b_g0, &Bs[bs_off0]);
    if (IS_FC1) GL_LDS16(b_g1, &Bs[bs_off1]);
    a_g += 32; b_g0 += 32;
    if (IS_FC1) b_g1 += 32;

    for (int ks = 0; ks < ITERS; ++ks) {
        __syncthreads();                  // drains GL(ks); prev readers done
        if (ks + 1 < ITERS) {             // prefetch K-step ks+1 into other buf
            const int nb = ((ks + 1) & 1);
            GL_LDS16(a_g, &As[nb * ASZ + as_off]);
            GL_LDS16(b_g0, &Bs[nb * BSZ + bs_off0]);
            if (IS_FC1) GL_LDS16(b_g1, &Bs[nb * BSZ + bs_off1]);
            a_g += 32; b_g0 += 32;
            if (IS_FC1) b_g1 += 32;
        }
        const int cb = (ks & 1);
        bf16x8 af[2], bfr[NB];
#pragma unroll
        for (int i = 0; i < 2; ++i) af[i] = *(const bf16x8*)&As[cb * ASZ + aoff[i]];
#pragma unroll
        for (int j = 0; j < NB; ++j) bfr[j] = *(const bf16x8*)&Bs[cb * BSZ + boff[j]];
#pragma unroll
        for (int i = 0; i < 2; ++i)
#pragma unroll
            for (int j = 0; j < NB; ++j)
                acc[i][j] = MFMA16(af[i], bfr[j], acc[i][j], 0, 0, 0);
    }

    // Epilogue. C/D layout (verified m89): col = lane&15, row = (lane>>4)*4 + reg.
#pragma unroll
    for (int j = 0; j < NB; ++j) {
        const int gn = n0 + wn + j * 16 + l15;
        if (IS_FC1) {
            __bf16* hb = (__bf16*)out_;
            const float bv = bias[e * H_DIM + gn];
#pragma unroll
            for (int i = 0; i < 2; ++i)
#pragma unroll
                for (int r = 0; r < 4; ++r) {
                    int m = m0 + wm + i * 16 + q * 4 + r;
                    if (m < Me) {
                        float v = acc[i][j][r] + bv;
                        hb[(size_t)(off + m) * H_DIM + gn] = (__bf16)fmaxf(v, 0.f);
                    }
                }
        } else {
            float* out = (float*)out_;
            const float bv = (kc == 0) ? bias[e * O_DIM + gn] : 0.f;
#pragma unroll
            for (int i = 0; i < 2; ++i)
#pragma unroll
                for (int r = 0; r < 4; ++r) {
                    int mrel = wm + i * 16 + q * 4 + r;
                    int m = m0 + mrel;
                    if (m < Me) {
                        int slot = off + m;
                        atomicAdd(&out[(size_t)toks[mrel] * O_DIM + gn],
                                  slot_wt[slot] * (acc[i][j][r] + bv));
                    }
                }
        }
    }
}

extern "C" void kernel_launch(void* const* d_in, const int* in_sizes, int n_in,
                              void* d_out, int out_size, void* d_ws, size_t ws_size,
                              hipStream_t stream)
{
    const float* x  = (const float*)d_in[0];
    const float* Wg = (const float*)d_in[1];
    const float* bg = (const float*)d_in[2];
    const float* W1 = (const float*)d_in[3];
    const float* b1 = (const float*)d_in[4];
    const float* W2 = (const float*)d_in[5];
    const float* b2 = (const float*)d_in[6];
    float* out = (float*)d_out;
    char* ws = (char*)d_ws;

    int*    counts   = (int*)(ws + WS_COUNTS);
    int*    offsets  = (int*)(ws + WS_OFFSETS);
    int*    tok_e    = (int*)(ws + WS_TOK_E);
    float*  tok_w    = (float*)(ws + WS_TOK_W);
    int*    slot_tok = (int*)(ws + WS_SLOT_TOK);
    float*  slot_wt  = (float*)(ws + WS_SLOT_WT);
    __bf16* xb       = (__bf16*)(ws + WS_XB);
    __bf16* hb       = (__bf16*)(ws + WS_HB);
    __bf16* W1t      = (__bf16*)(ws + WS_W1T);
    __bf16* W2t      = (__bf16*)(ws + WS_W2T);

    prologue_kernel<<<4608, 256, 0, stream>>>(W1, W2, (const float4*)x,
                                              W1t, W2t, xb, (float4*)out, counts);
    gating_kernel<<<B_TOK / 4, 256, 0, stream>>>(x, Wg, bg, counts, tok_e, tok_w);
    scatter_kernel<<<1, B_TOK, 0, stream>>>(counts, tok_e, tok_w, offsets,
                                            slot_tok, slot_wt);
    // fc1: 16 n-tiles x up-to-32 m-tiles x 8 experts (~512 working blocks)
    moe_gemm<true><<<dim3(16, 32, 8), 256, 0, stream>>>(
        xb, W1t, b1, counts, offsets, slot_tok, slot_wt, hb);
    // fc2: 8 n-tiles x up-to-32 m-tiles x (8 experts * 2 split-K)
    moe_gemm<false><<<dim3(8, 32, 16), 256, 0, stream>>>(
        hb, W2t, b2, counts, offsets, slot_tok, slot_wt, out);
}

// Round 6
// 156.866 us; speedup vs baseline: 1.3187x; 1.3187x over previous
//
#include <hip/hip_runtime.h>
#include <math.h>

// MoE top-2-of-8: B=1024, I=512, H=2048, O=512, E=8, K=2.
// R6: weight-stationary GEMM blocks. Each block converts its own W n-panel
// fp32->bf16 [n][k] into LDS once (no transpose prologue, W read exactly once
// from HBM), then m-loops over the expert's tokens with a reg->LDS A pipeline
// (global loads overlap MFMA; vmcnt wait sits at the ds_write after compute).
// Dense grids (fc1 512 blocks, fc2 256) -> even CU distribution. fc2 writes
// split-K partials to y4 (coalesced, no atomics); combine sums deterministically.

#define B_TOK 1024
#define I_DIM 512
#define H_DIM 2048
#define O_DIM 512
#define E_NUM 8

#define WS_COUNTS   0                    // 8 ints (written by scatter)
#define WS_OFFSETS  32                   // 8 ints
#define WS_TOK_E    64                   // [1024][2] int
#define WS_TOK_W    8256                 // [1024][2] float
#define WS_SLOT_TOK 16448                // [2048] int
#define WS_SLOT_WT  24640                // [2048] float
#define WS_TOK_SLOT 32832                // [1024][2] int
#define WS_XB       65536                // [1024][512] bf16 = 1 MB
#define WS_HB       (WS_XB + 1048576)    // [2048][2048] bf16 = 8 MB
#define WS_Y4       (WS_HB + 8388608)    // [4][2048][512] f32 = 16 MB

typedef __attribute__((ext_vector_type(8))) __bf16 bf16x8;
typedef __attribute__((ext_vector_type(4))) __bf16 bf16x4;
typedef __attribute__((ext_vector_type(4))) float f32x4;

#define MFMA16 __builtin_amdgcn_mfma_f32_16x16x32_bf16

// ---------------------------------------------------------------------------
// Gating: one wave per token. Also converts the token's x row to bf16 (xb).
__global__ __launch_bounds__(256) void gating_kernel(
    const float* __restrict__ x, const float* __restrict__ Wg,
    const float* __restrict__ bg, __bf16* __restrict__ xb,
    int* __restrict__ tok_e, float* __restrict__ tok_w)
{
    const int lane = threadIdx.x & 63;
    const int t = blockIdx.x * 4 + (threadIdx.x >> 6);
    const float4* x4 = (const float4*)(x + (size_t)t * I_DIM);
    float4 va = x4[lane], vb = x4[lane + 64];
    bf16x4 oa, ob;
    oa[0] = (__bf16)va.x; oa[1] = (__bf16)va.y;
    oa[2] = (__bf16)va.z; oa[3] = (__bf16)va.w;
    ob[0] = (__bf16)vb.x; ob[1] = (__bf16)vb.y;
    ob[2] = (__bf16)vb.z; ob[3] = (__bf16)vb.w;
    *(bf16x4*)(xb + (size_t)t * I_DIM + lane * 4) = oa;
    *(bf16x4*)(xb + (size_t)t * I_DIM + 256 + lane * 4) = ob;

    float acc[8];
#pragma unroll
    for (int e = 0; e < 8; ++e) acc[e] = 0.f;
    float xv[8] = {va.x, va.y, va.z, va.w, vb.x, vb.y, vb.z, vb.w};
#pragma unroll
    for (int u = 0; u < 8; ++u) {
        int i = (u < 4) ? (lane * 4 + u) : (256 + lane * 4 + u - 4);
        const float4* wr = (const float4*)(Wg + (size_t)i * 8);
        float4 wa = wr[0], wb2 = wr[1];
        acc[0] = fmaf(xv[u], wa.x, acc[0]);
        acc[1] = fmaf(xv[u], wa.y, acc[1]);
        acc[2] = fmaf(xv[u], wa.z, acc[2]);
        acc[3] = fmaf(xv[u], wa.w, acc[3]);
        acc[4] = fmaf(xv[u], wb2.x, acc[4]);
        acc[5] = fmaf(xv[u], wb2.y, acc[5]);
        acc[6] = fmaf(xv[u], wb2.z, acc[6]);
        acc[7] = fmaf(xv[u], wb2.w, acc[7]);
    }
#pragma unroll
    for (int off = 32; off > 0; off >>= 1)
#pragma unroll
        for (int e = 0; e < 8; ++e)
            acc[e] += __shfl_xor(acc[e], off, 64);
    if (lane == 0) {
        float l[8];
#pragma unroll
        for (int e = 0; e < 8; ++e) l[e] = acc[e] + bg[e];
        int e0 = 0;
        for (int e = 1; e < 8; ++e) if (l[e] > l[e0]) e0 = e;
        int e1 = (e0 == 0) ? 1 : 0;
        for (int e = 0; e < 8; ++e) {
            if (e == e0) continue;
            if (l[e] > l[e1]) e1 = e;
        }
        float w0 = 1.f / (1.f + expf(l[e1] - l[e0]));  // p0/(p0+p1)
        tok_e[t * 2]     = e0;
        tok_e[t * 2 + 1] = e1;
        tok_w[t * 2]     = w0;
        tok_w[t * 2 + 1] = 1.f - w0;
    }
}

// Single block: histogram -> prefix -> scatter into per-expert slot lists.
__global__ __launch_bounds__(1024) void scatter_kernel(
    const int* __restrict__ tok_e, const float* __restrict__ tok_w,
    int* __restrict__ counts, int* __restrict__ offsets,
    int* __restrict__ slot_token, float* __restrict__ slot_wt,
    int* __restrict__ tok_slot)
{
    __shared__ int hist[8], soff[8], scur[8];
    const int tid = threadIdx.x;
    if (tid < 8) { hist[tid] = 0; scur[tid] = 0; }
    __syncthreads();
    const int e0 = tok_e[tid * 2], e1 = tok_e[tid * 2 + 1];
    atomicAdd(&hist[e0], 1);
    atomicAdd(&hist[e1], 1);
    __syncthreads();
    if (tid == 0) {
        int run = 0;
        for (int e = 0; e < 8; ++e) { soff[e] = run; run += hist[e]; }
    }
    __syncthreads();
    if (tid < 8) { counts[tid] = hist[tid]; offsets[tid] = soff[tid]; }
#pragma unroll
    for (int k = 0; k < 2; ++k) {
        int e = tok_e[tid * 2 + k];
        int pos = atomicAdd(&scur[e], 1);
        int slot = soff[e] + pos;
        slot_token[slot] = tid;
        slot_wt[slot] = tok_w[tid * 2 + k];
        tok_slot[tid * 2 + k] = slot;
    }
}

// ---------------------------------------------------------------------------
// Weight-stationary GEMM block.  BM=64, K-chunk 512 (BK=128, 4 pipelined iters).
// IS_FC1: BN=32, A=xb gathered, W=W1[e] [512][2048], Out=hb bf16 (relu+bias)
// !IS_FC1:BN=64, A=hb direct (k0 chunk), W=W2[e] [2048][512], Out=y4[kc] f32
template <bool IS_FC1>
__global__ __launch_bounds__(256) void moe_gemm(
    const __bf16* __restrict__ A, const float* __restrict__ Wf,
    const float* __restrict__ bias,
    const int* __restrict__ counts, const int* __restrict__ offsets,
    const int* __restrict__ slot_token, float* __restrict__ y4,
    __bf16* __restrict__ hb)
{
    constexpr int N   = IS_FC1 ? H_DIM : O_DIM;   // W col count
    constexpr int K   = IS_FC1 ? I_DIM : H_DIM;   // W row count / A stride
    constexpr int BN  = IS_FC1 ? 32 : 64;
    constexpr int ITK = 4;                         // 512 / BK128

    const int e  = blockIdx.z;
    const int kc = IS_FC1 ? 0 : (int)blockIdx.y;
    const int n0 = blockIdx.x * BN;
    const int k0 = kc * 512;
    const int Me = counts[e];
    if (Me == 0) return;
    const int off = offsets[e];
    const float* W = Wf + (size_t)e * K * N;

    __shared__ __align__(16) __bf16 Bs[BN * 520];       // [n][k], +8 pad
    __shared__ __align__(16) __bf16 As[2][64 * 136];    // dbuf [m][k], +8 pad
    __shared__ __align__(16) unsigned char Sc[IS_FC1 ? 4096 : 16384];

    const int tid = threadIdx.x;
    const int lane = tid & 63, w = tid >> 6;

    // ---- B panel: W[k0..k0+512)[n0..n0+BN) fp32 -> Bs[n][k] bf16 ----
    {
        constexpr int KG = IS_FC1 ? 8 : 4;        // k-groups
        constexpr int KRUN = 512 / KG;            // k per thread
        const int bn = tid & (BN - 1);
        const int kg = tid / BN;
        const float* wp = W + (size_t)(k0 + kg * KRUN) * N + n0 + bn;
#pragma unroll 4
        for (int j = 0; j < KRUN / 4; ++j) {
            float v0 = wp[(size_t)(j * 4 + 0) * N];
            float v1 = wp[(size_t)(j * 4 + 1) * N];
            float v2 = wp[(size_t)(j * 4 + 2) * N];
            float v3 = wp[(size_t)(j * 4 + 3) * N];
            bf16x4 o;
            o[0] = (__bf16)v0; o[1] = (__bf16)v1;
            o[2] = (__bf16)v2; o[3] = (__bf16)v3;
            *(bf16x4*)&Bs[bn * 520 + kg * KRUN + j * 4] = o;
        }
    }
    __syncthreads();

    // ---- A staging map: thread -> row am, chunks (ac + 4j), j=0..3 ----
    const int am = tid >> 2;                       // 0..63
    const int ac = tid & 3;
    const int l15 = lane & 15, q = lane >> 4;
    const int wm = (w >> 1) * 32;
    const int wn = (w & 1) * (BN / 2);
    constexpr int NB = IS_FC1 ? 1 : 2;

    // first m-tile A base pointer
    const __bf16* aptr;
    {
        int m = am; if (m >= Me) m = Me - 1;
        if (IS_FC1) aptr = A + (size_t)slot_token[off + m] * K;
        else        aptr = A + (size_t)(off + m) * K + k0;
    }
    bf16x8 ar[4];
#pragma unroll
    for (int j = 0; j < 4; ++j)
        ar[j] = *(const bf16x8*)(aptr + (ac + 4 * j) * 8);

    for (int m0 = 0; m0 < Me; m0 += 64) {
        f32x4 acc[2][NB] = {};
#pragma unroll
        for (int it = 0; it < ITK; ++it) {
            __bf16* as = As[it & 1];
#pragma unroll
            for (int j = 0; j < 4; ++j)            // waits vmcnt for ar here
                *(bf16x8*)&as[am * 136 + (ac + 4 * j) * 8] = ar[j];
            __syncthreads();
            if (it + 1 < ITK) {
#pragma unroll
                for (int j = 0; j < 4; ++j)
                    ar[j] = *(const bf16x8*)(aptr + (it + 1) * 128 + (ac + 4 * j) * 8);
            } else if (m0 + 64 < Me) {             // preload next m-tile
                int m = m0 + 64 + am; if (m >= Me) m = Me - 1;
                if (IS_FC1) aptr = A + (size_t)slot_token[off + m] * K;
                else        aptr = A + (size_t)(off + m) * K + k0;
#pragma unroll
                for (int j = 0; j < 4; ++j)
                    ar[j] = *(const bf16x8*)(aptr + (ac + 4 * j) * 8);
            }
#pragma unroll
            for (int ks = 0; ks < 4; ++ks) {
                bf16x8 af0 = *(const bf16x8*)&as[(wm + l15) * 136 + ks * 32 + q * 8];
                bf16x8 af1 = *(const bf16x8*)&as[(wm + 16 + l15) * 136 + ks * 32 + q * 8];
#pragma unroll
                for (int jj = 0; jj < NB; ++jj) {
                    bf16x8 bf = *(const bf16x8*)
                        &Bs[(wn + jj * 16 + l15) * 520 + it * 128 + ks * 32 + q * 8];
                    acc[0][jj] = MFMA16(af0, bf, acc[0][jj], 0, 0, 0);
                    acc[1][jj] = MFMA16(af1, bf, acc[1][jj], 0, 0, 0);
                }
            }
        }

        // ---- epilogue via per-wave LDS transpose (coalesced stores) ----
        if (IS_FC1) {
            __bf16* sc = (__bf16*)Sc + w * 512;    // 32 rows x 16 cols
            const int gn = n0 + wn + l15;
            const float bv = bias[e * H_DIM + gn];
#pragma unroll
            for (int i = 0; i < 2; ++i)
#pragma unroll
                for (int r = 0; r < 4; ++r) {
                    float v = acc[i][0][r] + bv;
                    sc[(i * 16 + q * 4 + r) * 16 + l15] = (__bf16)fmaxf(v, 0.f);
                }
            __syncthreads();
            int rr = lane >> 1, h = lane & 1;
            int m = m0 + wm + rr;
            if (m < Me) {
                bf16x8 vv = *(const bf16x8*)&sc[rr * 16 + h * 8];
                *(bf16x8*)&hb[(size_t)(off + m) * H_DIM + n0 + wn + h * 8] = vv;
            }
            __syncthreads();                       // protect sc before next tile
        } else {
            float* sc = (float*)Sc + w * 1024;     // 32 rows x 32 cols
#pragma unroll
            for (int jj = 0; jj < 2; ++jj)
#pragma unroll
                for (int i = 0; i < 2; ++i)
#pragma unroll
                    for (int r = 0; r < 4; ++r)
                        sc[(i * 16 + q * 4 + r) * 32 + jj * 16 + l15] = acc[i][jj][r];
            __syncthreads();
            int rr = lane >> 1, h = lane & 1;
            int m = m0 + wm + rr;
            if (m < Me) {
                float* dst = y4 + ((size_t)kc * 2048 + off + m) * O_DIM + n0 + wn + h * 16;
#pragma unroll
                for (int p = 0; p < 4; ++p)
                    *(float4*)(dst + p * 4) = *(const float4*)&sc[rr * 32 + h * 16 + p * 4];
            }
            __syncthreads();
        }
    }
}

// out[t][c] = sum_k w_k * (b2[e_k][c] + sum_kc y4[kc][slot_k][c])
__global__ __launch_bounds__(256) void combine_kernel(
    const float* __restrict__ y4, const float* __restrict__ b2,
    const int* __restrict__ tok_slot, const int* __restrict__ tok_e,
    const float* __restrict__ tok_w, float* __restrict__ out)
{
    const int idx = blockIdx.x * 256 + threadIdx.x;   // B*O/4
    const int t = idx >> 7;
    const int c = (idx & 127) * 4;
    float4 sum = {0.f, 0.f, 0.f, 0.f};
#pragma unroll
    for (int k = 0; k < 2; ++k) {
        const int s = tok_slot[t * 2 + k];
        const int e = tok_e[t * 2 + k];
        const float wgt = tok_w[t * 2 + k];
        float4 a = *(const float4*)(b2 + (size_t)e * O_DIM + c);
#pragma unroll
        for (int kc = 0; kc < 4; ++kc) {
            float4 v = *(const float4*)(y4 + ((size_t)kc * 2048 + s) * O_DIM + c);
            a.x += v.x; a.y += v.y; a.z += v.z; a.w += v.w;
        }
        sum.x += wgt * a.x; sum.y += wgt * a.y;
        sum.z += wgt * a.z; sum.w += wgt * a.w;
    }
    *(float4*)(out + (size_t)t * O_DIM + c) = sum;
}

extern "C" void kernel_launch(void* const* d_in, const int* in_sizes, int n_in,
                              void* d_out, int out_size, void* d_ws, size_t ws_size,
                              hipStream_t stream)
{
    const float* x  = (const float*)d_in[0];
    const float* Wg = (const float*)d_in[1];
    const float* bg = (const float*)d_in[2];
    const float* W1 = (const float*)d_in[3];
    const float* b1 = (const float*)d_in[4];
    const float* W2 = (const float*)d_in[5];
    const float* b2 = (const float*)d_in[6];
    float* out = (float*)d_out;
    char* ws = (char*)d_ws;

    int*    counts   = (int*)(ws + WS_COUNTS);
    int*    offsets  = (int*)(ws + WS_OFFSETS);
    int*    tok_e    = (int*)(ws + WS_TOK_E);
    float*  tok_w    = (float*)(ws + WS_TOK_W);
    int*    slot_tok = (int*)(ws + WS_SLOT_TOK);
    float*  slot_wt  = (float*)(ws + WS_SLOT_WT);
    int*    tok_slot = (int*)(ws + WS_TOK_SLOT);
    __bf16* xb       = (__bf16*)(ws + WS_XB);
    __bf16* hb       = (__bf16*)(ws + WS_HB);
    float*  y4       = (float*)(ws + WS_Y4);
    (void)slot_wt;

    gating_kernel<<<B_TOK / 4, 256, 0, stream>>>(x, Wg, bg, xb, tok_e, tok_w);
    scatter_kernel<<<1, B_TOK, 0, stream>>>(tok_e, tok_w, counts, offsets,
                                            slot_tok, slot_wt, tok_slot);
    // fc1: 64 n-panels x 8 experts = 512 dense blocks (2/CU)
    moe_gemm<true><<<dim3(64, 1, 8), 256, 0, stream>>>(
        xb, W1, b1, counts, offsets, slot_tok, y4, hb);
    // fc2: 8 n-panels x 4 k-chunks x 8 experts = 256 dense blocks (1/CU)
    moe_gemm<false><<<dim3(8, 4, 8), 256, 0, stream>>>(
        hb, W2, b2, counts, offsets, slot_tok, y4, hb);
    combine_kernel<<<(B_TOK * O_DIM / 4) / 256, 256, 0, stream>>>(
        y4, b2, tok_slot, tok_e, tok_w, out);
}